// Round 6
// baseline (530.617 us; speedup 1.0000x reference)
//
#include <hip/hip_runtime.h>
#include <hip/hip_bf16.h>
#include <math.h>

typedef short short8 __attribute__((ext_vector_type(8)));
typedef float f32x4 __attribute__((ext_vector_type(4)));

__device__ __forceinline__ unsigned short f2bf(float x) {
    unsigned u = __float_as_uint(x);
    u += 0x7FFF + ((u >> 16) & 1);   // RNE
    return (unsigned short)(u >> 16);
}
__device__ __forceinline__ float bf2f(unsigned short h) {
    return __uint_as_float(((unsigned)h) << 16);
}

// Dekker-style split of 2 floats into packed bf16 hi words + bf16 lo words.
__device__ __forceinline__ void cvtpair(float f0, float f1, unsigned& hw, unsigned& lw) {
    __hip_bfloat162 h2 = __float22bfloat162_rn(float2{f0, f1});
    unsigned hu = *(unsigned*)&h2;
    float r0 = f0 - __uint_as_float(hu << 16);
    float r1 = f1 - __uint_as_float(hu & 0xFFFF0000u);
    __hip_bfloat162 l2 = __float22bfloat162_rn(float2{r0, r1});
    hw = hu;
    lw = *(unsigned*)&l2;
}

__device__ __forceinline__ void cvt8(const float4 a, const float4 b, short8& hi, short8& lo) {
    union { unsigned u[4]; short8 s; } H, L;
    cvtpair(a.x, a.y, H.u[0], L.u[0]);
    cvtpair(a.z, a.w, H.u[1], L.u[1]);
    cvtpair(b.x, b.y, H.u[2], L.u[2]);
    cvtpair(b.z, b.w, H.u[3], L.u[3]);
    hi = H.s; lo = L.s;
}

__device__ __forceinline__ float tanh10(float y) {
    float e = __expf(2.f * y);
    return 10.f * (e - 1.f) / (e + 1.f);
}

#define GLDS16(gp, lp)                                                        \
    __builtin_amdgcn_global_load_lds(                                         \
        (const __attribute__((address_space(1))) void*)(gp),                  \
        (__attribute__((address_space(3))) void*)(lp), 16, 0, 0)

#define SB0() __builtin_amdgcn_sched_barrier(0)

// ---------------------------------------------------------------------------
// K0: prep — Wt (fp32 transpose) + bf16 hi/lo split of W (row-major d x k),
// k-slot XOR swizzle pre-applied (phys_slot = slot ^ ((d>>1)&3)) so linear
// global_load_lds staging lands the R3-verified conflict-free read layout.
// ---------------------------------------------------------------------------
__global__ __launch_bounds__(256) void k_prep(const float* __restrict__ W,
                                              float* __restrict__ Wt,
                                              unsigned short* __restrict__ Whi,
                                              unsigned short* __restrict__ Wlo) {
    int d = blockIdx.x, k = threadIdx.x;
    float w = W[d * 256 + k];
    Wt[k * 256 + d] = w;
    unsigned short hi = f2bf(w);
    int s  = (k >> 3) & 3;
    int sp = s ^ ((d >> 1) & 3);
    int idx = d * 256 + (k & ~31) + sp * 8 + (k & 7);
    Whi[idx] = hi;
    Wlo[idx] = f2bf(w - bf2f(hi));
}

// ---------------------------------------------------------------------------
// K1: node projection (unchanged)
// ---------------------------------------------------------------------------
__global__ __launch_bounds__(256) void k_node_proj(const float* __restrict__ nodes,
                                                   const float* __restrict__ Wt,
                                                   const float* __restrict__ bias,
                                                   float* __restrict__ np_) {
    int row = blockIdx.x;
    int d = threadIdx.x;
    __shared__ float xl[256];
    xl[d] = nodes[row * 256 + d];
    __syncthreads();
    float a[8] = {0.f, 0.f, 0.f, 0.f, 0.f, 0.f, 0.f, 0.f};
#pragma unroll 4
    for (int k = 0; k < 256; k += 8) {
#pragma unroll
        for (int q = 0; q < 8; ++q)
            a[q] = fmaf(xl[k + q], Wt[(k + q) * 256 + d], a[q]);
    }
    np_[row * 256 + d] =
        bias[d] + ((a[0] + a[1]) + (a[2] + a[3])) + ((a[4] + a[5]) + (a[6] + a[7]));
}

// ---------------------------------------------------------------------------
// K2: MFMA edge scores — R3 structure at 2x occupancy.
//   512 threads = 8 waves; block = 256 edges x 128 dims; grid 2048, XCD-paired.
//   Wave w owns rows [w*32, w*32+32): mt=2, nt=8 -> acc = 64 AGPR, arch ~50
//   -> total <=128 regs -> 4 waves/SIMD (16 waves/CU), twice R3.
//   Per chunk vmcnt sequence (2)->(4)->(4): cvt half, reload that half's regs,
//   cvt other half, reload, MFMA [lgkm only], counted vmcnt(4)+barrier
//   (retires the 2 glds, keeps the 4 E loads in flight).
//   acc = Eh*Wh + Eh*Wl + El*Wh  (fp32 acc; dropped El*Wl ~2^-17 rel).
//   Softmax fused in epilogue.
// ---------------------------------------------------------------------------
__global__ __launch_bounds__(512, 4) void k_edge_mfma(const float* __restrict__ edges,
                                                      const unsigned short* __restrict__ Whi,
                                                      const unsigned short* __restrict__ Wlo,
                                                      const float* __restrict__ bias,
                                                      const float* __restrict__ np_,
                                                      float* __restrict__ attn) {
    __shared__ unsigned short Wbuf[2][2][128 * 32];  // [dbuf][hi/lo], 32 KB
    __shared__ float npi[128];
    __shared__ float sc[4][256];

    const int t = threadIdx.x;
    const int w = t >> 6, l = t & 63;
    const int col = l & 15, g = l >> 4;

    // XCD pairing: both dim-halves of a tile on the same XCD, contiguous range.
    const int p = blockIdx.x;
    const int L = (p & 7) * 256 + (p >> 3);
    const int tile = L >> 1, half = L & 1;
    const int bb = tile >> 8, ii = tile & 255;
    const int n0 = half * 128;               // dims n0..n0+127 (4 heads)

    if (t < 32)
        ((float4*)npi)[t] = ((const float4*)(np_ + (size_t)(bb * 256 + ii) * 256 + n0))[t];
    SB0();

    f32x4 acc[2][8];
#pragma unroll
    for (int mt = 0; mt < 2; ++mt)
#pragma unroll
        for (int nt = 0; nt < 8; ++nt) acc[mt][nt] = (f32x4){0.f, 0.f, 0.f, 0.f};

    // E base: row = w*32 + mt*16 + col, k-slice g*8
    const float* ea = edges + ((size_t)((bb * 256 + ii) * 256 + w * 32 + col)) * 256 + g * 8;
    // W staging: wave w stages rows w*16..w*16+15 of hi and of lo per chunk.
    // lane l -> row w*16 + (l>>2), 16B granule (l&3); source pre-swizzled.
    const size_t wg = (size_t)(n0 + w * 16 + (l >> 2)) * 256 + (l & 3) * 8;

    // ---- prologue: glds W(0) x2, E(0) x4, counted wait + barrier
    GLDS16(Whi + wg, &Wbuf[0][0][(w * 16) * 32]);
    GLDS16(Wlo + wg, &Wbuf[0][1][(w * 16) * 32]);
    SB0();
    float4 e[2][2];
    e[0][0] = *(const float4*)(ea);
    e[0][1] = *(const float4*)(ea + 4);
    e[1][0] = *(const float4*)(ea + 4096);
    e[1][1] = *(const float4*)(ea + 4096 + 4);
    SB0();
    // retires the 2 glds (+npi for wave 0); 4 E loads stay in flight
    asm volatile("s_waitcnt vmcnt(4)\n\ts_barrier" ::: "memory");

    // swizzled B read: phys_slot = g ^ (((nt*16+col)>>1)&3) = g ^ ((col>>1)&3)
    const int swb = (g ^ ((col >> 1) & 3)) << 3;

    short8 Ah[2], Al[2];

#pragma unroll
    for (int kc = 0; kc < 8; ++kc) {
        // ---- cvt half 0 (waits vmcnt(2): e[1] pair still in flight)
        cvt8(e[0][0], e[0][1], Ah[0], Al[0]);
        SB0();
        if (kc < 7) {
            // vm: glds W(kc+1) x2, then reload e[0] with E(kc+1) rows mt=0
            const int nb = (kc + 1) & 1;
            const size_t kofs = (size_t)(kc + 1) * 32;
            GLDS16(Whi + wg + kofs, &Wbuf[nb][0][(w * 16) * 32]);
            GLDS16(Wlo + wg + kofs, &Wbuf[nb][1][(w * 16) * 32]);
            e[0][0] = *(const float4*)(ea + (kc + 1) * 32);
            e[0][1] = *(const float4*)(ea + (kc + 1) * 32 + 4);
            SB0();
        }
        // ---- cvt half 1 (waits vmcnt(4): glds + e[0]' stay in flight)
        cvt8(e[1][0], e[1][1], Ah[1], Al[1]);
        SB0();
        if (kc < 7) {
            e[1][0] = *(const float4*)(ea + (kc + 1) * 32 + 4096);
            e[1][1] = *(const float4*)(ea + (kc + 1) * 32 + 4096 + 4);
            SB0();
        }
        // ---- MFMA phase on buf[kc&1] (lgkm waits only)
        const unsigned short* bh = &Wbuf[kc & 1][0][0] + col * 32 + swb;
        const unsigned short* bl = &Wbuf[kc & 1][1][0] + col * 32 + swb;
        __builtin_amdgcn_s_setprio(1);
#pragma unroll
        for (int nt = 0; nt < 8; ++nt) {
            short8 Bh = *(const short8*)(bh + nt * 512);
            short8 Bl = *(const short8*)(bl + nt * 512);
            acc[0][nt] = __builtin_amdgcn_mfma_f32_16x16x32_bf16(Ah[0], Bh, acc[0][nt], 0, 0, 0);
            acc[1][nt] = __builtin_amdgcn_mfma_f32_16x16x32_bf16(Ah[1], Bh, acc[1][nt], 0, 0, 0);
            acc[0][nt] = __builtin_amdgcn_mfma_f32_16x16x32_bf16(Ah[0], Bl, acc[0][nt], 0, 0, 0);
            acc[1][nt] = __builtin_amdgcn_mfma_f32_16x16x32_bf16(Ah[1], Bl, acc[1][nt], 0, 0, 0);
            acc[0][nt] = __builtin_amdgcn_mfma_f32_16x16x32_bf16(Al[0], Bh, acc[0][nt], 0, 0, 0);
            acc[1][nt] = __builtin_amdgcn_mfma_f32_16x16x32_bf16(Al[1], Bh, acc[1][nt], 0, 0, 0);
        }
        __builtin_amdgcn_s_setprio(0);
        SB0();
        if (kc < 7) {
            // counted drain: retires the 2 glds; 4 E loads remain in flight
            asm volatile("s_waitcnt vmcnt(4)\n\ts_barrier" ::: "memory");
        }
    }

    // ---- epilogue: scores for the 4 heads of this half
    const float isq = 0.17677669529663687f;  // 1/sqrt(32)
    float bv[8], nv[8];
#pragma unroll
    for (int nt = 0; nt < 8; ++nt) {
        int dl = nt * 16 + col;
        bv[nt] = bias[n0 + dl];
        nv[nt] = npi[dl];
    }
#pragma unroll
    for (int mt = 0; mt < 2; ++mt) {
#pragma unroll
        for (int r = 0; r < 4; ++r) {
            int el = w * 32 + mt * 16 + g * 4 + r;   // j index 0..255
            const float* npj = np_ + (size_t)(bb * 256 + el) * 256 + n0;
            float pp, s0 = 0.f, s1 = 0.f, s2 = 0.f, s3 = 0.f;
            pp = acc[mt][0][r] + bv[0]; s0 += (pp + nv[0]) * (pp + npj[col]);
            pp = acc[mt][1][r] + bv[1]; s0 += (pp + nv[1]) * (pp + npj[16 + col]);
            pp = acc[mt][2][r] + bv[2]; s1 += (pp + nv[2]) * (pp + npj[32 + col]);
            pp = acc[mt][3][r] + bv[3]; s1 += (pp + nv[3]) * (pp + npj[48 + col]);
            pp = acc[mt][4][r] + bv[4]; s2 += (pp + nv[4]) * (pp + npj[64 + col]);
            pp = acc[mt][5][r] + bv[5]; s2 += (pp + nv[5]) * (pp + npj[80 + col]);
            pp = acc[mt][6][r] + bv[6]; s3 += (pp + nv[6]) * (pp + npj[96 + col]);
            pp = acc[mt][7][r] + bv[7]; s3 += (pp + nv[7]) * (pp + npj[112 + col]);
#pragma unroll
            for (int m = 1; m < 16; m <<= 1) {
                s0 += __shfl_xor(s0, m, 64);
                s1 += __shfl_xor(s1, m, 64);
                s2 += __shfl_xor(s2, m, 64);
                s3 += __shfl_xor(s3, m, 64);
            }
            if (col == 0) {
                sc[0][el] = tanh10(s0 * isq);
                sc[1][el] = tanh10(s1 * isq);
                sc[2][el] = tanh10(s2 * isq);
                sc[3][el] = tanh10(s3 * isq);
            }
        }
    }
    __syncthreads();

    // ---- fused softmax: waves 0..3 normalize head rows (half*4 + w)
    if (w < 4) {
        float4 v = *(float4*)&sc[w][l * 4];
        float m = fmaxf(fmaxf(v.x, v.y), fmaxf(v.z, v.w));
#pragma unroll
        for (int s = 1; s < 64; s <<= 1) m = fmaxf(m, __shfl_xor(m, s, 64));
        v.x = __expf(v.x - m); v.y = __expf(v.y - m);
        v.z = __expf(v.z - m); v.w = __expf(v.w - m);
        float sum = v.x + v.y + v.z + v.w;
#pragma unroll
        for (int s = 1; s < 64; s <<= 1) sum += __shfl_xor(sum, s, 64);
        float inv = 1.f / sum;
        v.x *= inv; v.y *= inv; v.z *= inv; v.w *= inv;
        *(float4*)(attn + (((size_t)(bb * 8 + half * 4 + w) * 256 + ii) << 8) + l * 4) = v;
    }
}

// ---------------------------------------------------------------------------
// K4: out = proj(attn @ np) (unchanged)
// ---------------------------------------------------------------------------
__global__ __launch_bounds__(256) void k_out(const float* __restrict__ attn,
                                             const float* __restrict__ np_,
                                             const float* __restrict__ Wt,
                                             const float* __restrict__ bias,
                                             float* __restrict__ out) {
    int bi = blockIdx.x;
    int bb = bi >> 8, ii = bi & 255;
    int d = threadIdx.x;
    __shared__ float at[8 * 256];
    __shared__ float xl[256];
#pragma unroll
    for (int s = 0; s < 2; ++s) {
        int idx = d + s * 256;
        int h = idx >> 6, q = idx & 63;
        ((float4*)at)[idx] =
            ((const float4*)(attn + ((size_t)(bb * 8 + h) * 256 + ii) * 256))[q];
    }
    __syncthreads();
    int h = d >> 5;
    const float* npb = np_ + (size_t)bb * 65536 + d;
    const float* ath = at + h * 256;
    float a[8] = {0.f, 0.f, 0.f, 0.f, 0.f, 0.f, 0.f, 0.f};
#pragma unroll 2
    for (int j = 0; j < 256; j += 8) {
#pragma unroll
        for (int q = 0; q < 8; ++q)
            a[q] = fmaf(ath[j + q], npb[(size_t)(j + q) * 256], a[q]);
    }
    xl[d] = ((a[0] + a[1]) + (a[2] + a[3])) + ((a[4] + a[5]) + (a[6] + a[7]));
    __syncthreads();
    float c[8] = {bias[d], 0.f, 0.f, 0.f, 0.f, 0.f, 0.f, 0.f};
#pragma unroll 2
    for (int k = 0; k < 256; k += 8) {
#pragma unroll
        for (int q = 0; q < 8; ++q)
            c[q] = fmaf(xl[k + q], Wt[(k + q) * 256 + d], c[q]);
    }
    out[bi * 256 + d] =
        ((c[0] + c[1]) + (c[2] + c[3])) + ((c[4] + c[5]) + (c[6] + c[7]));
}

// ---------------------------------------------------------------------------
extern "C" void kernel_launch(void* const* d_in, const int* in_sizes, int n_in,
                              void* d_out, int out_size, void* d_ws, size_t ws_size,
                              hipStream_t stream) {
    (void)in_sizes; (void)n_in; (void)out_size; (void)ws_size;
    const float* nodes = (const float*)d_in[0];
    const float* edges = (const float*)d_in[1];
    const float* W     = (const float*)d_in[2];
    const float* bias  = (const float*)d_in[3];

    float* out  = (float*)d_out;            // (4,256,256)
    float* attn = out + 262144;             // (4,8,256,256)

    float* np_ = (float*)d_ws;              // 262144 floats
    float* Wt  = np_ + 262144;              // 65536 floats
    unsigned short* Whi = (unsigned short*)(Wt + 65536);  // 65536 bf16
    unsigned short* Wlo = Whi + 65536;                    // 65536 bf16

    hipLaunchKernelGGL(k_prep,      dim3(256),  dim3(256), 0, stream, W, Wt, Whi, Wlo);
    hipLaunchKernelGGL(k_node_proj, dim3(1024), dim3(256), 0, stream, nodes, Wt, bias, np_);
    hipLaunchKernelGGL(k_edge_mfma, dim3(2048), dim3(512), 0, stream, edges, Whi, Wlo, bias, np_, attn);
    hipLaunchKernelGGL(k_out,       dim3(1024), dim3(256), 0, stream, attn, np_, Wt, bias, out);
}

// Round 7
// 470.016 us; speedup vs baseline: 1.1289x; 1.1289x over previous
//
#include <hip/hip_runtime.h>
#include <hip/hip_bf16.h>
#include <math.h>

typedef short short8 __attribute__((ext_vector_type(8)));
typedef float f32x4 __attribute__((ext_vector_type(4)));

__device__ __forceinline__ unsigned short f2bf(float x) {
    unsigned u = __float_as_uint(x);
    u += 0x7FFF + ((u >> 16) & 1);   // RNE
    return (unsigned short)(u >> 16);
}
__device__ __forceinline__ float bf2f(unsigned short h) {
    return __uint_as_float(((unsigned)h) << 16);
}

// Dekker-style split of 2 floats into packed bf16 hi words + bf16 lo words.
__device__ __forceinline__ void cvtpair(float f0, float f1, unsigned& hw, unsigned& lw) {
    __hip_bfloat162 h2 = __float22bfloat162_rn(float2{f0, f1});
    unsigned hu = *(unsigned*)&h2;
    float r0 = f0 - __uint_as_float(hu << 16);
    float r1 = f1 - __uint_as_float(hu & 0xFFFF0000u);
    __hip_bfloat162 l2 = __float22bfloat162_rn(float2{r0, r1});
    hw = hu;
    lw = *(unsigned*)&l2;
}

__device__ __forceinline__ void cvt8(const float4 a, const float4 b, short8& hi, short8& lo) {
    union { unsigned u[4]; short8 s; } H, L;
    cvtpair(a.x, a.y, H.u[0], L.u[0]);
    cvtpair(a.z, a.w, H.u[1], L.u[1]);
    cvtpair(b.x, b.y, H.u[2], L.u[2]);
    cvtpair(b.z, b.w, H.u[3], L.u[3]);
    hi = H.s; lo = L.s;
}

__device__ __forceinline__ float tanh10(float y) {
    float e = __expf(2.f * y);
    return 10.f * (e - 1.f) / (e + 1.f);
}

#define GLDS16(gp, lp)                                                        \
    __builtin_amdgcn_global_load_lds(                                         \
        (const __attribute__((address_space(1))) void*)(gp),                  \
        (__attribute__((address_space(3))) void*)(lp), 16, 0, 0)

#define SB0() __builtin_amdgcn_sched_barrier(0)

// ---------------------------------------------------------------------------
// K0: prep — Wt (fp32 transpose) + bf16 hi/lo split of W (row-major d x k),
// k-slot XOR swizzle pre-applied (phys_slot = slot ^ ((d>>1)&3)) so linear
// global_load_lds staging lands the R3-verified conflict-free read layout.
// ---------------------------------------------------------------------------
__global__ __launch_bounds__(256) void k_prep(const float* __restrict__ W,
                                              float* __restrict__ Wt,
                                              unsigned short* __restrict__ Whi,
                                              unsigned short* __restrict__ Wlo) {
    int d = blockIdx.x, k = threadIdx.x;
    float w = W[d * 256 + k];
    Wt[k * 256 + d] = w;
    unsigned short hi = f2bf(w);
    int s  = (k >> 3) & 3;
    int sp = s ^ ((d >> 1) & 3);
    int idx = d * 256 + (k & ~31) + sp * 8 + (k & 7);
    Whi[idx] = hi;
    Wlo[idx] = f2bf(w - bf2f(hi));
}

// ---------------------------------------------------------------------------
// K1: node projection — 2 rows per block (grid 512).  The 256 Wt loads per
// thread now feed 2 outputs -> Wt L2 traffic halves (268 -> 134 MB).
// Per-output accumulation chain identical to before (bitwise-same np_).
// ---------------------------------------------------------------------------
__global__ __launch_bounds__(256) void k_node_proj(const float* __restrict__ nodes,
                                                   const float* __restrict__ Wt,
                                                   const float* __restrict__ bias,
                                                   float* __restrict__ np_) {
    int r0 = blockIdx.x * 2;
    int d = threadIdx.x;
    __shared__ float xl[2][256];
    if (d < 128)
        ((float4*)xl)[d] = ((const float4*)(nodes + (size_t)r0 * 256))[d];
    __syncthreads();
    float a[2][8];
#pragma unroll
    for (int s = 0; s < 2; ++s)
#pragma unroll
        for (int q = 0; q < 8; ++q) a[s][q] = 0.f;
#pragma unroll 4
    for (int k = 0; k < 256; k += 8) {
        float wv[8];
#pragma unroll
        for (int q = 0; q < 8; ++q) wv[q] = Wt[(k + q) * 256 + d];
#pragma unroll
        for (int s = 0; s < 2; ++s)
#pragma unroll
            for (int q = 0; q < 8; ++q)
                a[s][q] = fmaf(xl[s][k + q], wv[q], a[s][q]);
    }
#pragma unroll
    for (int s = 0; s < 2; ++s)
        np_[(size_t)(r0 + s) * 256 + d] =
            bias[d] + ((a[s][0] + a[s][1]) + (a[s][2] + a[s][3])) +
                      ((a[s][4] + a[s][5]) + (a[s][6] + a[s][7]));
}

// ---------------------------------------------------------------------------
// K2: MFMA edge scores — R3 structure EXACTLY (best measured: 187 us).
//   Block = 256 edges (full j row of one (b,i)) x 128 dims (4 heads).
//   grid = 2048, XCD-paired.  Wave w owns j in [w*64, w*64+64): mt=4, nt=8.
//   Per chunk: cvt E(kc) [covered by prev MFMA phase]; glds W(kc+1) x4;
//   E(kc+1) x8; MFMA [lgkm only]; s_waitcnt vmcnt(8)+s_barrier (counted:
//   retires glds, E stays in flight).
//   acc = Eh*Wh + Eh*Wl + El*Wh  (fp32 acc; dropped El*Wl ~2^-17 rel).
//   Softmax fused in epilogue.
// ---------------------------------------------------------------------------
__global__ __launch_bounds__(256, 2) void k_edge_mfma(const float* __restrict__ edges,
                                                      const unsigned short* __restrict__ Whi,
                                                      const unsigned short* __restrict__ Wlo,
                                                      const float* __restrict__ bias,
                                                      const float* __restrict__ np_,
                                                      float* __restrict__ attn) {
    __shared__ unsigned short Wbuf[2][2][128 * 32];  // [dbuf][hi/lo], 32 KB
    __shared__ float npi[128];
    __shared__ float sc[4][256];

    const int t = threadIdx.x;
    const int w = t >> 6, l = t & 63;
    const int col = l & 15, g = l >> 4;
    const int wrow = l >> 2, wq = l & 3;     // W staging lane mapping

    // XCD pairing: both dim-halves of a tile on the same XCD, contiguous range.
    const int p = blockIdx.x;
    const int L = (p & 7) * 256 + (p >> 3);
    const int tile = L >> 1, half = L & 1;
    const int bb = tile >> 8, ii = tile & 255;
    const int n0 = half * 128;               // dims n0..n0+127 (4 heads)

    if (t < 32)
        ((float4*)npi)[t] = ((const float4*)(np_ + (size_t)(bb * 256 + ii) * 256 + n0))[t];
    SB0();

    f32x4 acc[4][8];
#pragma unroll
    for (int mt = 0; mt < 4; ++mt)
#pragma unroll
        for (int nt = 0; nt < 8; ++nt) acc[mt][nt] = (f32x4){0.f, 0.f, 0.f, 0.f};

    // E base: row = w*64 + mt*16 + col, k-slice g*8
    const float* ea = edges + ((size_t)((bb * 256 + ii) * 256 + w * 64 + col)) * 256 + g * 8;
    // W staging global offsets (source pre-swizzled); wave w stages dims w*32..+32
    const size_t wg0 = (size_t)(n0 + w * 32 + wrow) * 256 + wq * 8;
    const size_t wg1 = wg0 + 16 * 256;

    // ---- prologue: stage W(0), then E(0) loads, counted wait + barrier
    GLDS16(Whi + wg0, &Wbuf[0][0][(w * 32) * 32]);
    GLDS16(Wlo + wg0, &Wbuf[0][1][(w * 32) * 32]);
    GLDS16(Whi + wg1, &Wbuf[0][0][(w * 32 + 16) * 32]);
    GLDS16(Wlo + wg1, &Wbuf[0][1][(w * 32 + 16) * 32]);
    SB0();
    float4 e[4][2];
#pragma unroll
    for (int mt = 0; mt < 4; ++mt) {
        e[mt][0] = *(const float4*)(ea + mt * 4096);
        e[mt][1] = *(const float4*)(ea + mt * 4096 + 4);
    }
    SB0();
    asm volatile("s_waitcnt vmcnt(8)\n\ts_barrier" ::: "memory");

    // swizzled B read base: phys_slot = g ^ ((row>>1)&3); row = nt*16+col and
    // nt*16 ≡ 0 (mod 4) -> XOR term depends only on col.
    const int swb = (g ^ ((col >> 1) & 3)) << 3;

    short8 Ah[4], Al[4];

#pragma unroll
    for (int kc = 0; kc < 8; ++kc) {
        // ---- convert E(kc): compiler's vmcnt wait here is covered by the
        // previous chunk's MFMA phase (E was issued one chunk ago).
#pragma unroll
        for (int mt = 0; mt < 4; ++mt)
            cvt8(e[mt][0], e[mt][1], Ah[mt], Al[mt]);
        SB0();
        if (kc < 7) {
            // vm ops 1-4: stage W(kc+1) into the other buffer
            const int nb = (kc + 1) & 1;
            const size_t kofs = (size_t)(kc + 1) * 32;
            GLDS16(Whi + wg0 + kofs, &Wbuf[nb][0][(w * 32) * 32]);
            GLDS16(Wlo + wg0 + kofs, &Wbuf[nb][1][(w * 32) * 32]);
            GLDS16(Whi + wg1 + kofs, &Wbuf[nb][0][(w * 32 + 16) * 32]);
            GLDS16(Wlo + wg1 + kofs, &Wbuf[nb][1][(w * 32 + 16) * 32]);
            SB0();
            // vm ops 5-12: E(kc+1) prefetch (HBM, stays in flight past barrier)
#pragma unroll
            for (int mt = 0; mt < 4; ++mt) {
                e[mt][0] = *(const float4*)(ea + (kc + 1) * 32 + mt * 4096);
                e[mt][1] = *(const float4*)(ea + (kc + 1) * 32 + mt * 4096 + 4);
            }
            SB0();
        }
        // ---- MFMA phase on buf[kc&1] (lgkm waits only)
        const unsigned short* bh = &Wbuf[kc & 1][0][0] + col * 32 + swb;
        const unsigned short* bl = &Wbuf[kc & 1][1][0] + col * 32 + swb;
        __builtin_amdgcn_s_setprio(1);
#pragma unroll
        for (int nt = 0; nt < 8; ++nt) {
            short8 Bh = *(const short8*)(bh + nt * 512);
            short8 Bl = *(const short8*)(bl + nt * 512);
#pragma unroll
            for (int mt = 0; mt < 4; ++mt) {
                acc[mt][nt] = __builtin_amdgcn_mfma_f32_16x16x32_bf16(Ah[mt], Bh, acc[mt][nt], 0, 0, 0);
                acc[mt][nt] = __builtin_amdgcn_mfma_f32_16x16x32_bf16(Ah[mt], Bl, acc[mt][nt], 0, 0, 0);
                acc[mt][nt] = __builtin_amdgcn_mfma_f32_16x16x32_bf16(Al[mt], Bh, acc[mt][nt], 0, 0, 0);
            }
        }
        __builtin_amdgcn_s_setprio(0);
        SB0();
        if (kc < 7) {
            // counted drain: retires the 4 glds (oldest); 8 E loads remain in flight
            asm volatile("s_waitcnt vmcnt(8)\n\ts_barrier" ::: "memory");
        }
    }

    // ---- epilogue: scores for the 4 heads of this half
    const float isq = 0.17677669529663687f;  // 1/sqrt(32)
    float bv[8], nv[8];
#pragma unroll
    for (int nt = 0; nt < 8; ++nt) {
        int dl = nt * 16 + col;
        bv[nt] = bias[n0 + dl];
        nv[nt] = npi[dl];
    }
#pragma unroll
    for (int mt = 0; mt < 4; ++mt) {
#pragma unroll
        for (int r = 0; r < 4; ++r) {
            int el = w * 64 + mt * 16 + g * 4 + r;   // j index 0..255
            const float* npj = np_ + (size_t)(bb * 256 + el) * 256 + n0;
            float pp, s0 = 0.f, s1 = 0.f, s2 = 0.f, s3 = 0.f;
            pp = acc[mt][0][r] + bv[0]; s0 += (pp + nv[0]) * (pp + npj[col]);
            pp = acc[mt][1][r] + bv[1]; s0 += (pp + nv[1]) * (pp + npj[16 + col]);
            pp = acc[mt][2][r] + bv[2]; s1 += (pp + nv[2]) * (pp + npj[32 + col]);
            pp = acc[mt][3][r] + bv[3]; s1 += (pp + nv[3]) * (pp + npj[48 + col]);
            pp = acc[mt][4][r] + bv[4]; s2 += (pp + nv[4]) * (pp + npj[64 + col]);
            pp = acc[mt][5][r] + bv[5]; s2 += (pp + nv[5]) * (pp + npj[80 + col]);
            pp = acc[mt][6][r] + bv[6]; s3 += (pp + nv[6]) * (pp + npj[96 + col]);
            pp = acc[mt][7][r] + bv[7]; s3 += (pp + nv[7]) * (pp + npj[112 + col]);
#pragma unroll
            for (int m = 1; m < 16; m <<= 1) {
                s0 += __shfl_xor(s0, m, 64);
                s1 += __shfl_xor(s1, m, 64);
                s2 += __shfl_xor(s2, m, 64);
                s3 += __shfl_xor(s3, m, 64);
            }
            if (col == 0) {
                sc[0][el] = tanh10(s0 * isq);
                sc[1][el] = tanh10(s1 * isq);
                sc[2][el] = tanh10(s2 * isq);
                sc[3][el] = tanh10(s3 * isq);
            }
        }
    }
    __syncthreads();

    // ---- fused softmax: wave w normalizes head row (half*4 + w)
    {
        float4 v = *(float4*)&sc[w][l * 4];
        float m = fmaxf(fmaxf(v.x, v.y), fmaxf(v.z, v.w));
#pragma unroll
        for (int s = 1; s < 64; s <<= 1) m = fmaxf(m, __shfl_xor(m, s, 64));
        v.x = __expf(v.x - m); v.y = __expf(v.y - m);
        v.z = __expf(v.z - m); v.w = __expf(v.w - m);
        float sum = v.x + v.y + v.z + v.w;
#pragma unroll
        for (int s = 1; s < 64; s <<= 1) sum += __shfl_xor(sum, s, 64);
        float inv = 1.f / sum;
        v.x *= inv; v.y *= inv; v.z *= inv; v.w *= inv;
        *(float4*)(attn + (((size_t)(bb * 8 + half * 4 + w) * 256 + ii) << 8) + l * 4) = v;
    }
}

// ---------------------------------------------------------------------------
// K4: out = proj(attn @ np) — 2 i-rows per block (grid 512).  np_ and Wt
// loads shared across both rows -> L2 traffic halves (536 -> 268 MB).
// Per-output accumulation chain identical to before (bitwise-same out).
// ---------------------------------------------------------------------------
__global__ __launch_bounds__(256) void k_out(const float* __restrict__ attn,
                                             const float* __restrict__ np_,
                                             const float* __restrict__ Wt,
                                             const float* __restrict__ bias,
                                             float* __restrict__ out) {
    int blk = blockIdx.x;
    int bb = blk >> 7, i0 = (blk & 127) * 2;
    int d = threadIdx.x;
    __shared__ float at[2][8 * 256];
    __shared__ float xl[2][256];
#pragma unroll
    for (int s = 0; s < 2; ++s) {
#pragma unroll
        for (int st = 0; st < 2; ++st) {
            int idx = d + st * 256;
            int h = idx >> 6, q = idx & 63;
            ((float4*)at[s])[idx] =
                ((const float4*)(attn + ((size_t)(bb * 8 + h) * 256 + (i0 + s)) * 256))[q];
        }
    }
    __syncthreads();
    int h = d >> 5;
    const float* npb = np_ + (size_t)bb * 65536 + d;
    float a[2][8];
#pragma unroll
    for (int s = 0; s < 2; ++s)
#pragma unroll
        for (int q = 0; q < 8; ++q) a[s][q] = 0.f;
#pragma unroll 2
    for (int j = 0; j < 256; j += 8) {
        float wv[8];
#pragma unroll
        for (int q = 0; q < 8; ++q) wv[q] = npb[(size_t)(j + q) * 256];
#pragma unroll
        for (int s = 0; s < 2; ++s)
#pragma unroll
            for (int q = 0; q < 8; ++q)
                a[s][q] = fmaf(at[s][h * 256 + j + q], wv[q], a[s][q]);
    }
#pragma unroll
    for (int s = 0; s < 2; ++s)
        xl[s][d] = ((a[s][0] + a[s][1]) + (a[s][2] + a[s][3])) +
                   ((a[s][4] + a[s][5]) + (a[s][6] + a[s][7]));
    __syncthreads();
    float c[2][8];
#pragma unroll
    for (int s = 0; s < 2; ++s) {
        c[s][0] = bias[d];
#pragma unroll
        for (int q = 1; q < 8; ++q) c[s][q] = 0.f;
    }
#pragma unroll 2
    for (int k = 0; k < 256; k += 8) {
        float wv[8];
#pragma unroll
        for (int q = 0; q < 8; ++q) wv[q] = Wt[(k + q) * 256 + d];
#pragma unroll
        for (int s = 0; s < 2; ++s)
#pragma unroll
            for (int q = 0; q < 8; ++q)
                c[s][q] = fmaf(xl[s][k + q], wv[q], c[s][q]);
    }
#pragma unroll
    for (int s = 0; s < 2; ++s)
        out[(size_t)(bb * 256 + i0 + s) * 256 + d] =
            ((c[s][0] + c[s][1]) + (c[s][2] + c[s][3])) +
            ((c[s][4] + c[s][5]) + (c[s][6] + c[s][7]));
}

// ---------------------------------------------------------------------------
extern "C" void kernel_launch(void* const* d_in, const int* in_sizes, int n_in,
                              void* d_out, int out_size, void* d_ws, size_t ws_size,
                              hipStream_t stream) {
    (void)in_sizes; (void)n_in; (void)out_size; (void)ws_size;
    const float* nodes = (const float*)d_in[0];
    const float* edges = (const float*)d_in[1];
    const float* W     = (const float*)d_in[2];
    const float* bias  = (const float*)d_in[3];

    float* out  = (float*)d_out;            // (4,256,256)
    float* attn = out + 262144;             // (4,8,256,256)

    float* np_ = (float*)d_ws;              // 262144 floats
    float* Wt  = np_ + 262144;              // 65536 floats
    unsigned short* Whi = (unsigned short*)(Wt + 65536);  // 65536 bf16
    unsigned short* Wlo = Whi + 65536;                    // 65536 bf16

    hipLaunchKernelGGL(k_prep,      dim3(256),  dim3(256), 0, stream, W, Wt, Whi, Wlo);
    hipLaunchKernelGGL(k_node_proj, dim3(512),  dim3(256), 0, stream, nodes, Wt, bias, np_);
    hipLaunchKernelGGL(k_edge_mfma, dim3(2048), dim3(256), 0, stream, edges, Whi, Wlo, bias, np_, attn);
    hipLaunchKernelGGL(k_out,       dim3(512),  dim3(256), 0, stream, attn, np_, Wt, bias, out);
}